// Round 3
// baseline (324.767 us; speedup 1.0000x reference)
//
#include <hip/hip_runtime.h>
#include <hip/hip_cooperative_groups.h>

namespace cg = cooperative_groups;

#define DIM 512
#define NVEC4 (DIM / 4)   // 128 float4 per row
#define LMAX 512
#define MAXB 64           // cap on conserved rows per label (expected ~8)
#define PAIR_CAP 65536
#define GRID 1024
#define TPB 256

__device__ __forceinline__ float wave_reduce_sum(float v) {
#pragma unroll
    for (int m = 32; m > 0; m >>= 1) v += __shfl_xor(v, m, 64);
    return v;
}

// Dot of rows ia, ib (raw embeddings), cooperatively across one wave.
__device__ __forceinline__ float dot_rows(const float4* __restrict__ E4,
                                          int ia, int ib, int lane) {
    const float4* a = E4 + (size_t)ia * NVEC4;
    const float4* b = E4 + (size_t)ib * NVEC4;
    float4 x0 = a[lane], y0 = b[lane];
    float4 x1 = a[lane + 64], y1 = b[lane + 64];
    float s = x0.x * y0.x + x0.y * y0.y + x0.z * y0.z + x0.w * y0.w;
    s += x1.x * y1.x + x1.y * y1.y + x1.z * y1.z + x1.w * y1.w;
    return wave_reduce_sum(s);
}

__global__ void __launch_bounds__(TPB)
fused_kernel(const float* __restrict__ E,
             const int* __restrict__ labels,
             const int* __restrict__ graphs,
             const int* __restrict__ cats,
             const int* __restrict__ idx1,
             const int* __restrict__ idx2,
             int n, int S,
             float* __restrict__ invn,
             int* __restrict__ bcnt,
             int* __restrict__ blist,
             int* __restrict__ paircnt,
             int2* __restrict__ pairs,
             int* __restrict__ negcnt,
             int2* __restrict__ negp,
             float* __restrict__ sums,
             int* __restrict__ donecnt,
             float* __restrict__ out) {
    cg::grid_group grid = cg::this_grid();
    const int gtid = blockIdx.x * blockDim.x + threadIdx.x;
    const int gsize = gridDim.x * blockDim.x;
    const int lane = threadIdx.x & 63;

    // ---- Phase A: zero counters ----
    for (int i = gtid; i < LMAX; i += gsize) bcnt[i] = 0;
    if (gtid == 0) {
        *paircnt = 0; *negcnt = 0; *donecnt = 0;
        sums[0] = 0.0f; sums[1] = 0.0f;
    }
    grid.sync();

    // ---- Phase B: invnorm + bucket insert + neg validation ----
    {
        int gw = gtid >> 6, nw = gsize >> 6;
        for (int row = gw; row < n; row += nw) {
            const float4* a = (const float4*)E + (size_t)row * NVEC4;
            float4 x0 = a[lane], x1 = a[lane + 64];
            float s = x0.x * x0.x + x0.y * x0.y + x0.z * x0.z + x0.w * x0.w;
            s += x1.x * x1.x + x1.y * x1.y + x1.z * x1.z + x1.w * x1.w;
            s = wave_reduce_sum(s);
            if (lane == 0) invn[row] = 1.0f / fmaxf(sqrtf(s), 1e-12f);
        }
        for (int i = gtid; i < n; i += gsize) {
            if (cats[i] < 3) {
                int lbl = labels[i];
                int p = atomicAdd(&bcnt[lbl], 1);
                if (p < MAXB) blist[lbl * MAXB + p] = i;
            }
        }
        for (int s = gtid; s < S; s += gsize) {
            int i = idx1[s], j = idx2[s];
            if (graphs[i] != graphs[j] && labels[i] != labels[j] &&
                (cats[i] < 3 || cats[j] < 3)) {
                negp[atomicAdd(negcnt, 1)] = make_int2(i, j);
            }
        }
    }
    grid.sync();

    // ---- Phase C: pairgen (blocks < LMAX)  ||  neg dots (blocks >= LMAX) ----
    __shared__ float s_acc[2];
    if (threadIdx.x < 2) s_acc[threadIdx.x] = 0.0f;
    __syncthreads();

    int nn = *negcnt;   // final after sync
    if (blockIdx.x < LMAX) {
        int b = blockIdx.x;
        int g = min(bcnt[b], MAXB);
        int npr = g * (g - 1) / 2;
        const int* lst = blist + b * MAXB;
        for (int p = threadIdx.x; p < npr; p += blockDim.x) {
            int a = 0, rem = p;
            while (rem >= g - 1 - a) { rem -= g - 1 - a; ++a; }
            int bb = a + 1 + rem;
            int ia = lst[a], ib = lst[bb];
            if (graphs[ia] != graphs[ib]) {
                int slot = atomicAdd(paircnt, 1);
                if (slot < PAIR_CAP) pairs[slot] = make_int2(ia, ib);
            }
        }
    } else {
        int wid = threadIdx.x >> 6;
        int gw2 = (blockIdx.x - LMAX) * (blockDim.x >> 6) + wid;
        int nw2 = (gridDim.x - LMAX) * (blockDim.x >> 6);
        float accn = 0.0f;
        for (int t = gw2; t < nn; t += nw2) {
            int2 pr = negp[t];
            float d = dot_rows((const float4*)E, pr.x, pr.y, lane);
            if (lane == 0) accn += fmaxf(d * invn[pr.x] * invn[pr.y], 0.0f);
        }
        if (lane == 0 && accn != 0.0f) atomicAdd(&s_acc[1], accn);
    }
    __syncthreads();
    if (threadIdx.x == 0 && s_acc[1] != 0.0f) atomicAdd(&sums[1], s_acc[1]);
    grid.sync();

    // ---- Phase D: pos dots + completion-counter finalize ----
    if (threadIdx.x < 2) s_acc[threadIdx.x] = 0.0f;
    __syncthreads();

    int np = min(*paircnt, PAIR_CAP);
    int gw3 = gtid >> 6, nw3 = gsize >> 6;
    float accp = 0.0f;
    for (int t = gw3; t < np; t += nw3) {
        int2 pr = pairs[t];
        float d = dot_rows((const float4*)E, pr.x, pr.y, lane);
        if (lane == 0) accp += 1.0f - d * invn[pr.x] * invn[pr.y];
    }
    if (lane == 0 && accp != 0.0f) atomicAdd(&s_acc[0], accp);
    __syncthreads();

    if (threadIdx.x == 0) {
        if (s_acc[0] != 0.0f) atomicAdd(&sums[0], s_acc[0]);
        __threadfence();
        int prev = atomicAdd(donecnt, 1);
        if (prev == (int)gridDim.x - 1) {
            float ps = atomicAdd(&sums[0], 0.0f);   // coherent read
            float ns = atomicAdd(&sums[1], 0.0f);
            float pos = (np > 0) ? ps / (float)np : 0.0f;
            float neg = (nn > 0) ? ns / (float)nn : 0.0f;
            out[0] = pos + neg;
        }
    }
}

extern "C" void kernel_launch(void* const* d_in, const int* in_sizes, int n_in,
                              void* d_out, int out_size, void* d_ws, size_t ws_size,
                              hipStream_t stream) {
    const float* E    = (const float*)d_in[0];
    const int* labels = (const int*)d_in[1];
    const int* graphs = (const int*)d_in[2];
    const int* cats   = (const int*)d_in[3];
    const int* idx1   = (const int*)d_in[4];
    const int* idx2   = (const int*)d_in[5];
    int n = in_sizes[1];   // 8192
    int S = in_sizes[4];   // 5000

    // ws layout (8B-aligned by construction)
    char* p = (char*)d_ws;
    float* invn  = (float*)p;  p += (size_t)n * sizeof(float);
    int* bcnt    = (int*)p;    p += LMAX * sizeof(int);
    int* blist   = (int*)p;    p += (size_t)LMAX * MAXB * sizeof(int);
    int* paircnt = (int*)p;    p += sizeof(int);
    int* negcnt  = (int*)p;    p += sizeof(int);
    int* donecnt = (int*)p;    p += 2 * sizeof(int);   // keep 8B alignment
    float* sums  = (float*)p;  p += 2 * sizeof(float);
    int2* pairs  = (int2*)p;   p += (size_t)PAIR_CAP * sizeof(int2);
    int2* negp   = (int2*)p;
    float* out   = (float*)d_out;

    void* args[] = {
        (void*)&E, (void*)&labels, (void*)&graphs, (void*)&cats,
        (void*)&idx1, (void*)&idx2, (void*)&n, (void*)&S,
        (void*)&invn, (void*)&bcnt, (void*)&blist,
        (void*)&paircnt, (void*)&pairs, (void*)&negcnt, (void*)&negp,
        (void*)&sums, (void*)&donecnt, (void*)&out
    };
    hipLaunchCooperativeKernel((void*)fused_kernel, dim3(GRID), dim3(TPB),
                               args, 0, stream);
}

// Round 4
// 40.008 us; speedup vs baseline: 8.1176x; 8.1176x over previous
//
#include <hip/hip_runtime.h>

#define DIM 512
#define NVEC4 (DIM / 4)   // 128 float4 per row
#define LMAX 512          // labels in [0, 512)
#define MAXB 40           // cap on conserved rows per label (expected ~8)
#define NB_NEG 256
#define NB_TOTAL (LMAX + NB_NEG)
#define TPB 256
#define EPS 1e-12f

__device__ __forceinline__ float d4(const float4 a, const float4 b) {
    return a.x * b.x + a.y * b.y + a.z * b.z + a.w * b.w;
}

// Fused dot + squared norms of rows ia, ib across one wave (ia/ib uniform).
__device__ __forceinline__ void dot3_rows(const float4* __restrict__ E4,
                                          int ia, int ib, int lane,
                                          float& aa, float& ab, float& bb) {
    const float4* A = E4 + (size_t)ia * NVEC4;
    const float4* B = E4 + (size_t)ib * NVEC4;
    float4 x0 = A[lane], x1 = A[lane + 64];
    float4 y0 = B[lane], y1 = B[lane + 64];
    float saa = d4(x0, x0) + d4(x1, x1);
    float sab = d4(x0, y0) + d4(x1, y1);
    float sbb = d4(y0, y0) + d4(y1, y1);
#pragma unroll
    for (int m = 32; m > 0; m >>= 1) {
        saa += __shfl_xor(saa, m, 64);
        sab += __shfl_xor(sab, m, 64);
        sbb += __shfl_xor(sbb, m, 64);
    }
    aa = saa; ab = sab; bb = sbb;
}

__device__ __forceinline__ float cos_sim(float aa, float ab, float bb) {
    return ab / (fmaxf(sqrtf(aa), EPS) * fmaxf(sqrtf(bb), EPS));
}

// Blocks [0, LMAX): per-label scan + intra-bucket pair dots.
// Blocks [LMAX, NB_TOTAL): grid-stride waves over negative samples.
// Every block writes partials[blockIdx.x] = {psum, pcnt, nsum, ncnt}.
__global__ void __launch_bounds__(TPB)
mega_kernel(const float* __restrict__ E,
            const int* __restrict__ labels,
            const int* __restrict__ graphs,
            const int* __restrict__ cats,
            const int* __restrict__ idx1,
            const int* __restrict__ idx2,
            int n, int S,
            float4* __restrict__ partials) {
    __shared__ int idxs[MAXB];
    __shared__ int gcount;
    __shared__ float s_acc[4];   // psum, pcnt, nsum, ncnt
    int tid = threadIdx.x, lane = tid & 63, wid = tid >> 6;
    if (tid == 0) gcount = 0;
    if (tid < 4) s_acc[tid] = 0.0f;
    __syncthreads();

    const float4* E4 = (const float4*)E;

    if (blockIdx.x < LMAX) {
        int lbl = blockIdx.x;
        // --- scan: collect conserved rows with this label (int4-vectorized) ---
        const int4* lab4 = (const int4*)labels;
        int nv4 = n >> 2;
        for (int v = tid; v < nv4; v += TPB) {
            int4 l4 = lab4[v];
            int base = v << 2;
            if (l4.x == lbl && cats[base + 0] < 3) { int p = atomicAdd(&gcount, 1); if (p < MAXB) idxs[p] = base + 0; }
            if (l4.y == lbl && cats[base + 1] < 3) { int p = atomicAdd(&gcount, 1); if (p < MAXB) idxs[p] = base + 1; }
            if (l4.z == lbl && cats[base + 2] < 3) { int p = atomicAdd(&gcount, 1); if (p < MAXB) idxs[p] = base + 2; }
            if (l4.w == lbl && cats[base + 3] < 3) { int p = atomicAdd(&gcount, 1); if (p < MAXB) idxs[p] = base + 3; }
        }
        __syncthreads();

        int g = min(gcount, MAXB);
        int npr = g * (g - 1) / 2;
        float psum = 0.0f, pcnt = 0.0f;
        for (int p = wid; p < npr; p += (TPB >> 6)) {
            int a = 0, rem = p;
            while (rem >= g - 1 - a) { rem -= g - 1 - a; ++a; }
            int b = a + 1 + rem;
            int ia = idxs[a], ib = idxs[b];
            if (graphs[ia] != graphs[ib]) {
                float aa, ab, bb;
                dot3_rows(E4, ia, ib, lane, aa, ab, bb);
                if (lane == 0) {
                    psum += 1.0f - cos_sim(aa, ab, bb);
                    pcnt += 1.0f;
                }
            }
        }
        if (lane == 0 && pcnt != 0.0f) {
            atomicAdd(&s_acc[0], psum);
            atomicAdd(&s_acc[1], pcnt);
        }
    } else {
        // --- negative samples: wave-per-sample, grid-stride ---
        int gw = (blockIdx.x - LMAX) * (TPB >> 6) + wid;
        int nw = NB_NEG * (TPB >> 6);
        float nsum = 0.0f, ncnt = 0.0f;
        for (int s = gw; s < S; s += nw) {
            int i = idx1[s], j = idx2[s];
            if (graphs[i] != graphs[j] && labels[i] != labels[j] &&
                (cats[i] < 3 || cats[j] < 3)) {
                float aa, ab, bb;
                dot3_rows(E4, i, j, lane, aa, ab, bb);
                if (lane == 0) {
                    nsum += fmaxf(cos_sim(aa, ab, bb), 0.0f);   // MARGIN = 0
                    ncnt += 1.0f;
                }
            }
        }
        if (lane == 0 && ncnt != 0.0f) {
            atomicAdd(&s_acc[2], nsum);
            atomicAdd(&s_acc[3], ncnt);
        }
    }
    __syncthreads();
    if (tid == 0)
        partials[blockIdx.x] = make_float4(s_acc[0], s_acc[1], s_acc[2], s_acc[3]);
}

__global__ void __launch_bounds__(TPB)
finalize_kernel(const float4* __restrict__ partials, int nb,
                float* __restrict__ out) {
    __shared__ float s_acc[4];
    int tid = threadIdx.x, lane = tid & 63;
    if (tid < 4) s_acc[tid] = 0.0f;
    __syncthreads();

    float ps = 0.0f, pc = 0.0f, ns = 0.0f, nc = 0.0f;
    for (int i = tid; i < nb; i += TPB) {
        float4 v = partials[i];
        ps += v.x; pc += v.y; ns += v.z; nc += v.w;
    }
#pragma unroll
    for (int m = 32; m > 0; m >>= 1) {
        ps += __shfl_xor(ps, m, 64);
        pc += __shfl_xor(pc, m, 64);
        ns += __shfl_xor(ns, m, 64);
        nc += __shfl_xor(nc, m, 64);
    }
    if (lane == 0) {
        atomicAdd(&s_acc[0], ps);
        atomicAdd(&s_acc[1], pc);
        atomicAdd(&s_acc[2], ns);
        atomicAdd(&s_acc[3], nc);
    }
    __syncthreads();
    if (tid == 0) {
        float pos = (s_acc[1] > 0.0f) ? s_acc[0] / s_acc[1] : 0.0f;
        float neg = (s_acc[3] > 0.0f) ? s_acc[2] / s_acc[3] : 0.0f;
        out[0] = pos + neg;
    }
}

extern "C" void kernel_launch(void* const* d_in, const int* in_sizes, int n_in,
                              void* d_out, int out_size, void* d_ws, size_t ws_size,
                              hipStream_t stream) {
    const float* E    = (const float*)d_in[0];
    const int* labels = (const int*)d_in[1];
    const int* graphs = (const int*)d_in[2];
    const int* cats   = (const int*)d_in[3];
    const int* idx1   = (const int*)d_in[4];
    const int* idx2   = (const int*)d_in[5];
    int n = in_sizes[1];   // 8192
    int S = in_sizes[4];   // 5000

    float4* partials = (float4*)d_ws;   // NB_TOTAL slots, all written every call

    mega_kernel<<<NB_TOTAL, TPB, 0, stream>>>(E, labels, graphs, cats,
                                              idx1, idx2, n, S, partials);
    finalize_kernel<<<1, TPB, 0, stream>>>(partials, NB_TOTAL, (float*)d_out);
}

// Round 5
// 19.376 us; speedup vs baseline: 16.7611x; 2.0648x over previous
//
#include <hip/hip_runtime.h>

#define DIM 512
#define NVEC4 (DIM / 4)     // 128 float4 per row
#define LMAX 512            // labels in [0, 512)
#define MAXB 32             // cap on conserved rows per label (mean ~8, P(>32)~1e-10)
#define MAXPAIR (MAXB * (MAXB - 1) / 2)   // 496
#define NB_NEG 128
#define NB_TOTAL (LMAX + NB_NEG)
#define TPB 1024
#define NGROUPS (TPB / 16)  // 64 16-lane dot groups per block
#define EPS 1e-12f

__device__ __forceinline__ float d4(const float4 a, const float4 b) {
    return a.x * b.x + a.y * b.y + a.z * b.z + a.w * b.w;
}

// 16-lane-group fused dot + squared norms. gl = lane-in-group [0,16).
// Lanes of a group access interleaved float4s -> 256B coalesced segments.
__device__ __forceinline__ void dot3_16(const float4* __restrict__ E4,
                                        int ia, int ib, int gl,
                                        float& aa, float& ab, float& bb) {
    const float4* A = E4 + (size_t)ia * NVEC4;
    const float4* B = E4 + (size_t)ib * NVEC4;
    float saa = 0.0f, sab = 0.0f, sbb = 0.0f;
#pragma unroll
    for (int k = 0; k < 8; ++k) {
        float4 x = A[gl + 16 * k];
        float4 y = B[gl + 16 * k];
        saa += d4(x, x);
        sab += d4(x, y);
        sbb += d4(y, y);
    }
#pragma unroll
    for (int m = 8; m >= 1; m >>= 1) {   // reduce within aligned 16-lane group
        saa += __shfl_xor(saa, m, 64);
        sab += __shfl_xor(sab, m, 64);
        sbb += __shfl_xor(sbb, m, 64);
    }
    aa = saa; ab = sab; bb = sbb;
}

__device__ __forceinline__ float cos_sim(float aa, float ab, float bb) {
    return ab / (fmaxf(sqrtf(aa), EPS) * fmaxf(sqrtf(bb), EPS));
}

// Blocks [0, LMAX): per-label scan -> LDS pair list -> 64-way parallel dots.
// Blocks [LMAX, NB_TOTAL): 16-lane group per negative sample.
// Every block writes partials[blockIdx.x] = {psum, pcnt, nsum, ncnt}.
__global__ void __launch_bounds__(TPB)
mega_kernel(const float* __restrict__ E,
            const int* __restrict__ labels,
            const int* __restrict__ graphs,
            const int* __restrict__ cats,
            const int* __restrict__ idx1,
            const int* __restrict__ idx2,
            int n, int S,
            float4* __restrict__ partials) {
    __shared__ int idxs[MAXB];
    __shared__ int gcount;
    __shared__ int2 plist[MAXPAIR];
    __shared__ int pcount;
    __shared__ float s_acc[4];   // psum, pcnt, nsum, ncnt
    const int tid = threadIdx.x;
    const int grp = tid >> 4, gl = tid & 15;
    if (tid == 0) { gcount = 0; pcount = 0; }
    if (tid < 4) s_acc[tid] = 0.0f;
    __syncthreads();

    const float4* E4 = (const float4*)E;

    if (blockIdx.x < LMAX) {
        const int lbl = blockIdx.x;
        // --- scan: conserved rows with this label (int4-vectorized labels) ---
        const int4* lab4 = (const int4*)labels;
        int nv4 = n >> 2;
        for (int v = tid; v < nv4; v += TPB) {
            int4 l4 = lab4[v];
            int base = v << 2;
            if (l4.x == lbl && cats[base + 0] < 3) { int p = atomicAdd(&gcount, 1); if (p < MAXB) idxs[p] = base + 0; }
            if (l4.y == lbl && cats[base + 1] < 3) { int p = atomicAdd(&gcount, 1); if (p < MAXB) idxs[p] = base + 1; }
            if (l4.z == lbl && cats[base + 2] < 3) { int p = atomicAdd(&gcount, 1); if (p < MAXB) idxs[p] = base + 2; }
            if (l4.w == lbl && cats[base + 3] < 3) { int p = atomicAdd(&gcount, 1); if (p < MAXB) idxs[p] = base + 3; }
        }
        __syncthreads();

        // --- enumerate valid pairs into LDS (g*g <= 1024 = TPB: 1 cell/thread) ---
        int g = min(gcount, MAXB);
        if (tid < g * g) {
            int a = tid / g, b = tid - a * g;
            if (a < b) {
                int ia = idxs[a], ib = idxs[b];
                if (graphs[ia] != graphs[ib]) {
                    int slot = atomicAdd(&pcount, 1);
                    plist[slot] = make_int2(ia, ib);
                }
            }
        }
        __syncthreads();

        // --- 64 concurrent 16-lane dots over the pair list ---
        int np = pcount;
        float psum = 0.0f, pc = 0.0f;
        for (int p = grp; p < np; p += NGROUPS) {
            int2 pr = plist[p];
            float aa, ab, bb;
            dot3_16(E4, pr.x, pr.y, gl, aa, ab, bb);
            if (gl == 0) {
                psum += 1.0f - cos_sim(aa, ab, bb);
                pc += 1.0f;
            }
        }
        if (gl == 0 && pc != 0.0f) {
            atomicAdd(&s_acc[0], psum);
            atomicAdd(&s_acc[1], pc);
        }
    } else {
        // --- negative samples: one 16-lane group per sample ---
        int base = (blockIdx.x - LMAX) * NGROUPS;
        int stride = NB_NEG * NGROUPS;
        float nsum = 0.0f, nc = 0.0f;
        for (int s = base + grp; s < S; s += stride) {
            int i = idx1[s], j = idx2[s];
            if (graphs[i] != graphs[j] && labels[i] != labels[j] &&
                (cats[i] < 3 || cats[j] < 3)) {
                float aa, ab, bb;
                dot3_16(E4, i, j, gl, aa, ab, bb);
                if (gl == 0) {
                    nsum += fmaxf(cos_sim(aa, ab, bb), 0.0f);   // MARGIN = 0
                    nc += 1.0f;
                }
            }
        }
        if (gl == 0 && nc != 0.0f) {
            atomicAdd(&s_acc[2], nsum);
            atomicAdd(&s_acc[3], nc);
        }
    }
    __syncthreads();
    if (tid == 0)
        partials[blockIdx.x] = make_float4(s_acc[0], s_acc[1], s_acc[2], s_acc[3]);
}

__global__ void __launch_bounds__(256)
finalize_kernel(const float4* __restrict__ partials, int nb,
                float* __restrict__ out) {
    __shared__ float s_acc[4];
    int tid = threadIdx.x, lane = tid & 63;
    if (tid < 4) s_acc[tid] = 0.0f;
    __syncthreads();

    float ps = 0.0f, pc = 0.0f, ns = 0.0f, nc = 0.0f;
    for (int i = tid; i < nb; i += 256) {
        float4 v = partials[i];
        ps += v.x; pc += v.y; ns += v.z; nc += v.w;
    }
#pragma unroll
    for (int m = 32; m > 0; m >>= 1) {
        ps += __shfl_xor(ps, m, 64);
        pc += __shfl_xor(pc, m, 64);
        ns += __shfl_xor(ns, m, 64);
        nc += __shfl_xor(nc, m, 64);
    }
    if (lane == 0) {
        atomicAdd(&s_acc[0], ps);
        atomicAdd(&s_acc[1], pc);
        atomicAdd(&s_acc[2], ns);
        atomicAdd(&s_acc[3], nc);
    }
    __syncthreads();
    if (tid == 0) {
        float pos = (s_acc[1] > 0.0f) ? s_acc[0] / s_acc[1] : 0.0f;
        float neg = (s_acc[3] > 0.0f) ? s_acc[2] / s_acc[3] : 0.0f;
        out[0] = pos + neg;
    }
}

extern "C" void kernel_launch(void* const* d_in, const int* in_sizes, int n_in,
                              void* d_out, int out_size, void* d_ws, size_t ws_size,
                              hipStream_t stream) {
    const float* E    = (const float*)d_in[0];
    const int* labels = (const int*)d_in[1];
    const int* graphs = (const int*)d_in[2];
    const int* cats   = (const int*)d_in[3];
    const int* idx1   = (const int*)d_in[4];
    const int* idx2   = (const int*)d_in[5];
    int n = in_sizes[1];   // 8192
    int S = in_sizes[4];   // 5000

    float4* partials = (float4*)d_ws;   // NB_TOTAL slots, all written every call

    mega_kernel<<<NB_TOTAL, TPB, 0, stream>>>(E, labels, graphs, cats,
                                              idx1, idx2, n, S, partials);
    finalize_kernel<<<1, 256, 0, stream>>>(partials, NB_TOTAL, (float*)d_out);
}